// Round 1
// baseline (183.499 us; speedup 1.0000x reference)
//
#include <hip/hip_runtime.h>
#include <hip/hip_bf16.h>
#include <cstdint>
#include <cstddef>

// Problem constants
#define NB 512
#define NM 16
#define ND 128
#define NP 16
#define NT 4096

typedef __bf16 bf16x8 __attribute__((ext_vector_type(8)));
typedef __bf16 bf16x4 __attribute__((ext_vector_type(4)));
typedef float f32x4 __attribute__((ext_vector_type(4)));

static_assert(sizeof(bf16x8) == 16, "bf16x8 must be 16B");

__device__ __forceinline__ void gload_lds16(const void* g, void* l) {
  __builtin_amdgcn_global_load_lds(
      (const __attribute__((address_space(1))) unsigned int*)g,
      (__attribute__((address_space(3))) unsigned int*)l, 16, 0, 0);
}

// ---------------------------------------------------------------------------
// Kernel 1: blocks [0,512): new_state[b,m,:] = tanh(state@A_m + phi@B_m)
//           -> fp32 to d_out tail, bf16 to ws, s_sq[b*16+m] to ws
//           blocks [512,544): t_sq[t] + bf16 trajectories
// ---------------------------------------------------------------------------
__global__ __launch_bounds__(256) void prep_kernel(
    const float* __restrict__ phi, const float* __restrict__ state,
    const float* __restrict__ traj, const float* __restrict__ A,
    const float* __restrict__ Bin, float* __restrict__ ns_out,
    __bf16* __restrict__ ns_bf, __bf16* __restrict__ tj_bf,
    float* __restrict__ s_sq, float* __restrict__ t_sq) {
  __shared__ float sA[128 * 128];   // A[m] as [d][h]
  __shared__ float sSt[16 * 128];   // state rows
  __shared__ float sBin[16 * 128];  // B_in[m] as [p][h]
  __shared__ float sPhi[16 * 16];
  __shared__ float sRed[16 * 2];
  __shared__ float sPart[256];
  const int tid = threadIdx.x;
  const int bx = blockIdx.x;

  if (bx < 512) {
    const int m = bx & 15;
    const int b0 = (bx >> 4) * 16;
    const float4* A4 = (const float4*)(A + (size_t)m * 16384);
    float4* sA4 = (float4*)sA;
#pragma unroll
    for (int i = 0; i < 16; ++i) sA4[tid + i * 256] = A4[tid + i * 256];
    const float4* S4 = (const float4*)(state + (size_t)b0 * 128);
    float4* sSt4 = (float4*)sSt;
    sSt4[tid] = S4[tid];
    sSt4[tid + 256] = S4[tid + 256];
    const float4* B4 = (const float4*)(Bin + (size_t)m * 2048);
    float4* sBin4 = (float4*)sBin;
    sBin4[tid] = B4[tid];
    sBin4[tid + 256] = B4[tid + 256];
    sPhi[tid] = phi[b0 * 16 + tid];
    __syncthreads();

    const int h = tid & 127;   // output dim
    const int rg = tid >> 7;   // row group: 0 -> rows 0..7, 1 -> rows 8..15
    float acc[8];
#pragma unroll
    for (int j = 0; j < 8; ++j) acc[j] = 0.f;
    const float4* st4 = (const float4*)sSt;
    for (int dd = 0; dd < 32; ++dd) {
      const float a0 = sA[(dd * 4 + 0) * 128 + h];
      const float a1 = sA[(dd * 4 + 1) * 128 + h];
      const float a2 = sA[(dd * 4 + 2) * 128 + h];
      const float a3 = sA[(dd * 4 + 3) * 128 + h];
#pragma unroll
      for (int j = 0; j < 8; ++j) {
        const float4 sv = st4[(rg * 8 + j) * 32 + dd];  // broadcast within wave
        acc[j] = fmaf(sv.x, a0, acc[j]);
        acc[j] = fmaf(sv.y, a1, acc[j]);
        acc[j] = fmaf(sv.z, a2, acc[j]);
        acc[j] = fmaf(sv.w, a3, acc[j]);
      }
    }
#pragma unroll
    for (int p = 0; p < 16; ++p) {
      const float bv = sBin[p * 128 + h];
#pragma unroll
      for (int j = 0; j < 8; ++j)
        acc[j] = fmaf(sPhi[(rg * 8 + j) * 16 + p], bv, acc[j]);
    }

#pragma unroll
    for (int j = 0; j < 8; ++j) {
      const float v = tanhf(acc[j]);
      const int R = (b0 + rg * 8 + j) * 16 + m;  // GEMM row index b*M+m
      ns_out[(size_t)R * 128 + h] = v;
      ns_bf[(size_t)R * 128 + h] = (__bf16)v;
      float s = v * v;
#pragma unroll
      for (int o = 32; o > 0; o >>= 1) s += __shfl_xor(s, o, 64);
      if ((tid & 63) == 0) sRed[(rg * 8 + j) * 2 + ((tid >> 6) & 1)] = s;
    }
    __syncthreads();
    if (tid < 16)
      s_sq[(b0 + tid) * 16 + m] = sRed[tid * 2] + sRed[tid * 2 + 1];
  } else {
    // trajectory prep: 128 rows per block, 2 threads per row
    const int t0 = (bx - 512) * 128;
    const int row = t0 + (tid >> 1);
    const int half = tid & 1;
    const size_t base = (size_t)row * 128 + half * 64;
    const float4* T4 = (const float4*)traj;
    float s = 0.f;
#pragma unroll
    for (int i = 0; i < 16; ++i) {
      const float4 v = T4[base / 4 + i];
      s += v.x * v.x + v.y * v.y + v.z * v.z + v.w * v.w;
      bf16x4 o;
      o[0] = (__bf16)v.x;
      o[1] = (__bf16)v.y;
      o[2] = (__bf16)v.z;
      o[3] = (__bf16)v.w;
      *(bf16x4*)(tj_bf + base + i * 4) = o;
    }
    sPart[tid] = s;
    __syncthreads();
    if (tid < 128) t_sq[t0 + tid] = sPart[2 * tid] + sPart[2 * tid + 1];
  }
}

// ---------------------------------------------------------------------------
// Kernel 2: sim[R, t] = exp(-max(s_sq[R] + t_sq[t] - 2 * <ns[R,:], traj[t,:]>, 0))
// 128x128 output tile per block, bf16 MFMA 16x16x32, K=128 single stage.
// ---------------------------------------------------------------------------
__global__ __launch_bounds__(256) void sim_kernel(
    const __bf16* __restrict__ ns_bf, const __bf16* __restrict__ tj_bf,
    const float* __restrict__ s_sq, const float* __restrict__ t_sq,
    float* __restrict__ out) {
  __shared__ alignas(16) __bf16 sA[128 * 128];  // 32 KB: ns rows [row][k]
  __shared__ alignas(16) __bf16 sB[128 * 128];  // 32 KB: traj rows [t][k]
  __shared__ float sSq[128];
  __shared__ float sTq[128];
  const int tid = threadIdx.x;
  const int lane = tid & 63;
  const int w = tid >> 6;
  const int R0 = blockIdx.x * 128;
  const int C0 = blockIdx.y * 128;

  // async stage: both tiles are contiguous 32 KB chunks (256 B rows, unpadded)
  const char* gA = (const char*)(ns_bf + (size_t)R0 * 128);
  const char* gB = (const char*)(tj_bf + (size_t)C0 * 128);
#pragma unroll
  for (int it = 0; it < 8; ++it) {
    const int off = it * 4096 + w * 1024;  // wave-uniform LDS base; HW adds lane*16
    gload_lds16(gA + off + lane * 16, (char*)sA + off);
    gload_lds16(gB + off + lane * 16, (char*)sB + off);
  }
  if (tid < 128)
    sSq[tid] = s_sq[R0 + tid];
  else
    sTq[tid - 128] = t_sq[C0 + tid - 128];
  __syncthreads();  // compiler emits s_waitcnt vmcnt(0) here -> async loads done

  const int rbase = (w >> 1) * 64;  // wave's 64x64 quadrant
  const int cbase = (w & 1) * 64;
  const int l15 = lane & 15;
  const int quad = lane >> 4;

  f32x4 acc[4][4];
#pragma unroll
  for (int i = 0; i < 4; ++i)
#pragma unroll
    for (int j = 0; j < 4; ++j) acc[i][j] = (f32x4){0.f, 0.f, 0.f, 0.f};

#pragma unroll
  for (int ks = 0; ks < 4; ++ks) {
    const int koff = quad * 8 + ks * 32;
    bf16x8 af[4], bf[4];
#pragma unroll
    for (int i = 0; i < 4; ++i)
      af[i] = *(const bf16x8*)&sA[(rbase + i * 16 + l15) * 128 + koff];
#pragma unroll
    for (int i = 0; i < 4; ++i)
      bf[i] = *(const bf16x8*)&sB[(cbase + i * 16 + l15) * 128 + koff];
#pragma unroll
    for (int ri = 0; ri < 4; ++ri)
#pragma unroll
      for (int ci = 0; ci < 4; ++ci)
        acc[ri][ci] = __builtin_amdgcn_mfma_f32_16x16x32_bf16(
            af[ri], bf[ci], acc[ri][ci], 0, 0, 0);
  }

  // epilogue: C/D layout col = lane&15, row = quad*4 + reg
#pragma unroll
  for (int ri = 0; ri < 4; ++ri) {
    const int rl = rbase + ri * 16 + quad * 4;
#pragma unroll
    for (int ci = 0; ci < 4; ++ci) {
      const int cl = cbase + ci * 16 + l15;
      const float tq = sTq[cl];
      const size_t col = (size_t)(C0 + cl);
#pragma unroll
      for (int r = 0; r < 4; ++r) {
        const float d0 = sSq[rl + r] + tq - 2.f * acc[ri][ci][r];
        const float d = fmaxf(d0, 0.f);
        out[(size_t)(R0 + rl + r) * NT + col] = expf(-d);
      }
    }
  }
}

// ---------------------------------------------------------------------------
extern "C" void kernel_launch(void* const* d_in, const int* in_sizes, int n_in,
                              void* d_out, int out_size, void* d_ws,
                              size_t ws_size, hipStream_t stream) {
  (void)in_sizes; (void)n_in; (void)out_size; (void)ws_size;
  const float* phi   = (const float*)d_in[0];
  const float* state = (const float*)d_in[1];
  const float* traj  = (const float*)d_in[2];
  const float* A     = (const float*)d_in[3];
  const float* Bin   = (const float*)d_in[4];

  float* out = (float*)d_out;
  float* out_ns = out + (size_t)NB * NM * NT;  // second output: new_state fp32

  char* ws = (char*)d_ws;
  __bf16* ns_bf = (__bf16*)ws;                                  // 2 MB
  __bf16* tj_bf = (__bf16*)(ws + (2u << 20));                   // 1 MB
  float* s_sq   = (float*)(ws + (3u << 20));                    // 32 KB
  float* t_sq   = (float*)(ws + (3u << 20) + (32u << 10));      // 16 KB

  prep_kernel<<<544, 256, 0, stream>>>(phi, state, traj, A, Bin, out_ns, ns_bf,
                                       tj_bf, s_sq, t_sq);
  dim3 g2(NB * NM / 128, NT / 128);  // 64 x 32
  sim_kernel<<<g2, 256, 0, stream>>>(ns_bf, tj_bf, s_sq, t_sq, out);
}

// Round 2
// 168.676 us; speedup vs baseline: 1.0879x; 1.0879x over previous
//
#include <hip/hip_runtime.h>
#include <hip/hip_bf16.h>
#include <cstdint>
#include <cstddef>

// Problem constants
#define NB 512
#define NM 16
#define ND 128
#define NP 16
#define NT 4096

typedef __bf16 bf16x8 __attribute__((ext_vector_type(8)));
typedef float f32x4 __attribute__((ext_vector_type(4)));

static_assert(sizeof(bf16x8) == 16, "bf16x8 must be 16B");

__device__ __forceinline__ void gload_lds16(const void* g, void* l) {
  __builtin_amdgcn_global_load_lds(
      (const __attribute__((address_space(1))) unsigned int*)g,
      (__attribute__((address_space(3))) unsigned int*)l, 16, 0, 0);
}

// ---------------------------------------------------------------------------
// Kernel 1:
//  blocks [0,512): new_state[b,m,:] = tanh(state@A_m + phi@B_m)
//    -> fp32 to d_out tail, swizzled bf16 to ws, s_sq[b*16+m] to ws
//  blocks [512,544): t_sq[t] + swizzled bf16 trajectories
//  Swizzle: 16B chunk kb of row R stored at chunk (kb ^ (R&15)) -> conflict-
//  free ds_read_b128 fragment reads in kernel 2 (global_load_lds copies the
//  image verbatim, so the swizzle survives into LDS).
// ---------------------------------------------------------------------------
__global__ __launch_bounds__(256) void prep_kernel(
    const float* __restrict__ phi, const float* __restrict__ state,
    const float* __restrict__ traj, const float* __restrict__ A,
    const float* __restrict__ Bin, float* __restrict__ ns_out,
    __bf16* __restrict__ ns_bf, __bf16* __restrict__ tj_bf,
    float* __restrict__ s_sq, float* __restrict__ t_sq) {
  __shared__ alignas(16) float sSt[16 * 128];   // state rows (8 KB)
  __shared__ alignas(16) float sPhi[16 * 16];   // phi rows (1 KB)
  __shared__ alignas(16) float sRes[16 * 128];  // result tile for repack (8 KB)
  const int tid = threadIdx.x;
  const int bx = blockIdx.x;

  if (bx < 512) {
    const int m = bx & 15;
    const int b0 = (bx >> 4) * 16;
    // stage state tile + phi tile (small, coalesced)
    const float4* S4 = (const float4*)(state + (size_t)b0 * 128);
    float4* sSt4 = (float4*)sSt;
    sSt4[tid] = S4[tid];
    sSt4[tid + 256] = S4[tid + 256];
    sPhi[tid] = phi[b0 * 16 + tid];
    __syncthreads();

    const int h2 = tid & 63;         // h in {h2, h2+64}
    const int rgrp = tid >> 6;       // wave id == row group (rows rgrp*4..+3)
    const float* Ap = A + (size_t)m * 16384 + h2;
    const float* Bp = Bin + (size_t)m * 2048 + h2;

    float acc[2][4];
#pragma unroll
    for (int hi = 0; hi < 2; ++hi)
#pragma unroll
      for (int j = 0; j < 4; ++j) acc[hi][j] = 0.f;

    // state @ A_m : A direct from global (L2-resident, coalesced 256B rows)
#pragma unroll 4
    for (int c = 0; c < 32; ++c) {
      float a0[4], a1[4];
#pragma unroll
      for (int u = 0; u < 4; ++u) {
        a0[u] = Ap[(size_t)(c * 4 + u) * 128];
        a1[u] = Ap[(size_t)(c * 4 + u) * 128 + 64];
      }
#pragma unroll
      for (int j = 0; j < 4; ++j) {
        const f32x4 sv = *(const f32x4*)&sSt[(rgrp * 4 + j) * 128 + c * 4];
#pragma unroll
        for (int u = 0; u < 4; ++u) {
          acc[0][j] = fmaf(sv[u], a0[u], acc[0][j]);
          acc[1][j] = fmaf(sv[u], a1[u], acc[1][j]);
        }
      }
    }
    // phi @ B_m
#pragma unroll
    for (int pc = 0; pc < 4; ++pc) {
      float b0v[4], b1v[4];
#pragma unroll
      for (int u = 0; u < 4; ++u) {
        b0v[u] = Bp[(size_t)(pc * 4 + u) * 128];
        b1v[u] = Bp[(size_t)(pc * 4 + u) * 128 + 64];
      }
#pragma unroll
      for (int j = 0; j < 4; ++j) {
        const f32x4 pv = *(const f32x4*)&sPhi[(rgrp * 4 + j) * 16 + pc * 4];
#pragma unroll
        for (int u = 0; u < 4; ++u) {
          acc[0][j] = fmaf(pv[u], b0v[u], acc[0][j]);
          acc[1][j] = fmaf(pv[u], b1v[u], acc[1][j]);
        }
      }
    }

    // tanh, outputs, per-row squared-norm (whole row lives in one wave)
#pragma unroll
    for (int j = 0; j < 4; ++j) {
      const int row = rgrp * 4 + j;
      const int R = (b0 + row) * 16 + m;
      const float v0 = tanhf(acc[0][j]);
      const float v1 = tanhf(acc[1][j]);
      ns_out[(size_t)R * 128 + h2] = v0;
      ns_out[(size_t)R * 128 + h2 + 64] = v1;
      sRes[row * 128 + h2] = v0;
      sRes[row * 128 + h2 + 64] = v1;
      float s = v0 * v0 + v1 * v1;
#pragma unroll
      for (int o = 32; o > 0; o >>= 1) s += __shfl_xor(s, o);
      if (h2 == 0) s_sq[R] = s;
    }
    __syncthreads();

    // repack to swizzled bf16: one 16B chunk per thread
    {
      const int row = tid >> 4;      // 0..15
      const int kb = tid & 15;       // chunk index
      const f32x4 r0 = *(const f32x4*)&sRes[row * 128 + kb * 8];
      const f32x4 r1 = *(const f32x4*)&sRes[row * 128 + kb * 8 + 4];
      bf16x8 o;
#pragma unroll
      for (int i = 0; i < 4; ++i) {
        o[i] = (__bf16)r0[i];
        o[i + 4] = (__bf16)r1[i];
      }
      const int R = (b0 + row) * 16 + m;      // R & 15 == m
      *(bf16x8*)(ns_bf + (size_t)R * 128 + ((kb ^ m) * 8)) = o;
    }
  } else {
    // trajectory prep: 128 rows per block, 2 threads per row
    const int t0 = (bx - 512) * 128;
    const int t = t0 + (tid >> 1);
    const int half = tid & 1;
    float s = 0.f;
#pragma unroll
    for (int q = 0; q < 8; ++q) {
      const int kb = half * 8 + q;
      const f32x4 v0 = *(const f32x4*)&traj[(size_t)t * 128 + kb * 8];
      const f32x4 v1 = *(const f32x4*)&traj[(size_t)t * 128 + kb * 8 + 4];
      s += v0[0] * v0[0] + v0[1] * v0[1] + v0[2] * v0[2] + v0[3] * v0[3];
      s += v1[0] * v1[0] + v1[1] * v1[1] + v1[2] * v1[2] + v1[3] * v1[3];
      bf16x8 o;
#pragma unroll
      for (int i = 0; i < 4; ++i) {
        o[i] = (__bf16)v0[i];
        o[i + 4] = (__bf16)v1[i];
      }
      *(bf16x8*)(tj_bf + (size_t)t * 128 + ((kb ^ (t & 15)) * 8)) = o;
    }
    s += __shfl_xor(s, 1);  // combine the row's two halves (adjacent lanes)
    if (half == 0) t_sq[t] = s;
  }
}

// ---------------------------------------------------------------------------
// Kernel 2: sim[R, t] = exp(-max(s_sq[R] + t_sq[t] - 2 * <ns[R,:], traj[t,:]>, 0))
// 128x128 tile per block; bf16 MFMA 16x16x32 with traj as the A operand so
// each lane's 4 acc regs are 4 consecutive t -> float4 stores.
// ---------------------------------------------------------------------------
__global__ __launch_bounds__(256) void sim_kernel(
    const __bf16* __restrict__ ns_bf, const __bf16* __restrict__ tj_bf,
    const float* __restrict__ s_sq, const float* __restrict__ t_sq,
    float* __restrict__ out) {
  __shared__ alignas(16) __bf16 sA[128 * 128];  // 32 KB: ns rows (swizzled)
  __shared__ alignas(16) __bf16 sB[128 * 128];  // 32 KB: traj rows (swizzled)
  __shared__ float sSq[128];
  __shared__ float sTq[128];
  const int tid = threadIdx.x;
  const int lane = tid & 63;
  const int w = tid >> 6;
  const int R0 = blockIdx.x * 128;
  const int C0 = blockIdx.y * 128;

  // async stage: contiguous 32 KB images (swizzle is inside rows, preserved)
  const char* gA = (const char*)(ns_bf + (size_t)R0 * 128);
  const char* gB = (const char*)(tj_bf + (size_t)C0 * 128);
#pragma unroll
  for (int it = 0; it < 8; ++it) {
    const int off = it * 4096 + w * 1024;  // wave-uniform base; HW adds lane*16
    gload_lds16(gA + off + lane * 16, (char*)sA + off);
    gload_lds16(gB + off + lane * 16, (char*)sB + off);
  }
  if (tid < 128)
    sSq[tid] = s_sq[R0 + tid];
  else
    sTq[tid - 128] = t_sq[C0 + tid - 128];
  __syncthreads();

  const int rbase = (w >> 1) * 64;  // ns quadrant
  const int cbase = (w & 1) * 64;   // traj quadrant
  const int l15 = lane & 15;
  const int quad = lane >> 4;

  f32x4 acc[4][4];  // [ri = ns subtile][ci = traj subtile]
#pragma unroll
  for (int i = 0; i < 4; ++i)
#pragma unroll
    for (int j = 0; j < 4; ++j) acc[i][j] = (f32x4){0.f, 0.f, 0.f, 0.f};

#pragma unroll
  for (int ks = 0; ks < 4; ++ks) {
    const int kb = quad + ks * 4;          // unswizzled chunk index
    const int koff = (kb ^ l15) * 8;       // swizzled element offset
    bf16x8 af[4], bfr[4];
#pragma unroll
    for (int i = 0; i < 4; ++i)
      af[i] = *(const bf16x8*)&sA[(rbase + i * 16 + l15) * 128 + koff];
#pragma unroll
    for (int i = 0; i < 4; ++i)
      bfr[i] = *(const bf16x8*)&sB[(cbase + i * 16 + l15) * 128 + koff];
#pragma unroll
    for (int ri = 0; ri < 4; ++ri)
#pragma unroll
      for (int ci = 0; ci < 4; ++ci)
        acc[ri][ci] = __builtin_amdgcn_mfma_f32_16x16x32_bf16(
            bfr[ci], af[ri], acc[ri][ci], 0, 0, 0);  // A=traj, B=ns
  }

  // D layout: col(lane&15) = ns row, row(quad*4+reg) = t -> float4 along t
#pragma unroll
  for (int ri = 0; ri < 4; ++ri) {
    const int nsrow = rbase + ri * 16 + l15;
    const float sq = sSq[nsrow];
    float* orow = out + (size_t)(R0 + nsrow) * NT + C0;
#pragma unroll
    for (int ci = 0; ci < 4; ++ci) {
      const int t4 = cbase + ci * 16 + quad * 4;
      const f32x4 tq = *(const f32x4*)&sTq[t4];
      f32x4 r;
#pragma unroll
      for (int k = 0; k < 4; ++k) {
        const float d = fmaxf(sq + tq[k] - 2.f * acc[ri][ci][k], 0.f);
        r[k] = __expf(-d);
      }
      *(f32x4*)&orow[t4] = r;
    }
  }
}

// ---------------------------------------------------------------------------
extern "C" void kernel_launch(void* const* d_in, const int* in_sizes, int n_in,
                              void* d_out, int out_size, void* d_ws,
                              size_t ws_size, hipStream_t stream) {
  (void)in_sizes; (void)n_in; (void)out_size; (void)ws_size;
  const float* phi   = (const float*)d_in[0];
  const float* state = (const float*)d_in[1];
  const float* traj  = (const float*)d_in[2];
  const float* A     = (const float*)d_in[3];
  const float* Bin   = (const float*)d_in[4];

  float* out = (float*)d_out;
  float* out_ns = out + (size_t)NB * NM * NT;  // second output: new_state fp32

  char* ws = (char*)d_ws;
  __bf16* ns_bf = (__bf16*)ws;                                  // 2 MB
  __bf16* tj_bf = (__bf16*)(ws + (2u << 20));                   // 1 MB
  float* s_sq   = (float*)(ws + (3u << 20));                    // 32 KB
  float* t_sq   = (float*)(ws + (3u << 20) + (32u << 10));      // 16 KB

  prep_kernel<<<544, 256, 0, stream>>>(phi, state, traj, A, Bin, out_ns, ns_bf,
                                       tj_bf, s_sq, t_sq);
  dim3 g2(NB * NM / 128, NT / 128);  // 64 x 32
  sim_kernel<<<g2, 256, 0, stream>>>(ns_bf, tj_bf, s_sq, t_sq, out);
}